// Round 4
// baseline (337.899 us; speedup 1.0000x reference)
//
#include <hip/hip_runtime.h>
#include <stdint.h>

typedef unsigned int  u32;
typedef unsigned short u16;

#define B_ROWS 131072
#define P_PRED 64
#define C_CLS  128
#define NPAIR  384               // C*L raw words for dtype detection
#define RPB    64                // rows per block
#define TPB    256               // 4 waves: wave q handles clauses [q*32, q*32+32)
#define LSTR   65                // LDS row stride (+1 pad -> 2-way bank alias, free)
#define ACC_OFF (RPB * LSTR)     // float-index offset of accumulator region
#define LOG2E  1.4426950408889634f

#if __has_builtin(__builtin_amdgcn_exp2f)
#define EXP2F(x) __builtin_amdgcn_exp2f(x)
#else
#define EXP2F(x) exp2f(x)
#endif

#if __has_builtin(__builtin_amdgcn_rcpf)
#define RCPF(x) __builtin_amdgcn_rcpf(x)
#else
#define RCPF(x) (1.0f / (x))
#endif

// Clause record (8 dwords = 32 B -> one s_load_dwordx8, wave-uniform):
//   w[l] = idx_l | (sign_l>0 ? 0 : 0x80000000)   l = 0,1,2
//   sw[l] = sign_l * clamp(weight_c, 0, 500)
__device__ __forceinline__ float bf16_to_f(u16 u) {
    return __uint_as_float(((u32)u) << 16);
}
__device__ __forceinline__ u16 f_to_bf16(float f) {
    u32 u = __float_as_uint(f);
    u += 0x7FFFu + ((u >> 16) & 1u);   // RNE
    return (u16)(u >> 16);
}
__device__ __forceinline__ float sxor(float a, u32 m) {
    return __uint_as_float(__float_as_uint(a) ^ m);
}
__device__ __forceinline__ void lds_fadd(float* p, float v) {
    // LDS float add, workgroup scope -> ds_add_f32
    __hip_atomic_fetch_add(p, v, __ATOMIC_RELAXED, __HIP_MEMORY_SCOPE_WORKGROUP);
}

// ---------------------------------------------------------------------------
// Prep: dtype detection + 128-entry clause table (no atomics, no CSR).
// ---------------------------------------------------------------------------
__global__ void ke_prep(const u32* __restrict__ lidx_w,
                        const u32* __restrict__ sb_w,
                        const u32* __restrict__ w_w,
                        u32* __restrict__ recs,     // [128*8] dwords
                        u32* __restrict__ flags) {  // [1]: 1 = bf16 floats
    __shared__ int sidx[NPAIR];
    __shared__ int ssb[NPAIR];
    __shared__ int det[3];  // [0] idx-int64, [1] sb-int64, [2] floats-bf16
    const int t = threadIdx.x;
    if (t < 3) det[t] = 1;
    __syncthreads();
    if (t < NPAIR / 2) {
        if (lidx_w[2 * t + 1] != 0u) det[0] = 0;   // benign race (all write 0)
        if (sb_w[2 * t + 1]   != 0u) det[1] = 0;
    }
    if (t == 0 && (w_w[0] & 0xFFFFu) == 0u) det[2] = 0;
    __syncthreads();
    if (t < NPAIR) {
        sidx[t] = (int)(det[0] ? lidx_w[2 * t] : lidx_w[t]);
        ssb[t]  = (int)(det[1] ? sb_w[2 * t]   : sb_w[t]);
    }
    __syncthreads();
    if (t < C_CLS) {
        const int c = t;
        float wraw = det[2] ? bf16_to_f((u16)(w_w[c / 2] >> ((c & 1) * 16)))
                            : __uint_as_float(w_w[c]);
        float wc = fminf(fmaxf(wraw, 0.0f), 500.0f);
        u32* r = recs + c * 8;
#pragma unroll
        for (int l = 0; l < 3; ++l) {
            int b = ssb[c * 3 + l];
            r[l]     = (u32)sidx[c * 3 + l] | (b ? 0u : 0x80000000u);
            r[3 + l] = __float_as_uint(b ? wc : -wc);
        }
        r[6] = 0u;
        r[7] = 0u;
    }
    if (t == 0) flags[0] = (u32)det[2];
}

// ---------------------------------------------------------------------------
// Main, clause-centric: 64 rows/block staged in LDS (x log2e); a second LDS
// region holds per-row accumulators at a constant byte delta (ds imm offset).
// Wave q processes clauses [32q, 32q+32) for all 64 rows (lane = row);
// per clause: 3 ds_read + 3 exp2 + 1 rcp + 3 ds_add_f32. Records arrive via
// wave-uniform s_load_dwordx8. Races across waves resolved by ds_add_f32.
// ---------------------------------------------------------------------------
__global__ __launch_bounds__(TPB, 4)
void ke_main(const void* __restrict__ atoms_v,
             const u32* __restrict__ recs_u,
             const u32* __restrict__ flags,
             void* __restrict__ out_v) {
    __shared__ float lds[2 * RPB * LSTR];   // [0,ACC_OFF): atoms  [ACC_OFF,..): acc
    const int tid = threadIdx.x;
    const int row = tid & (RPB - 1);
    const int q = __builtin_amdgcn_readfirstlane(tid >> 6);  // 0..3, SGPR
    const int rowBase = blockIdx.x * RPB;
    const bool bf16m = (flags[0] != 0u);

    // ---- zero accumulator region (17 ds_writes/thread)
    for (int i = tid; i < RPB * LSTR; i += TPB) lds[ACC_OFF + i] = 0.0f;

    // ---- stage 64 rows of atoms, scaled by log2(e)
    if (bf16m) {
        const u16* gbase = (const u16*)atoms_v + (size_t)rowBase * P_PRED;
#pragma unroll
        for (int pass = 0; pass < 2; ++pass) {
            int flat = pass * (TPB * 8) + tid * 8;   // 8 bf16 / thread
            uint4 v = *(const uint4*)(gbase + flat);
            int r = flat >> 6, col = flat & 63;
            float* dst = &lds[r * LSTR + col];
            dst[0] = __uint_as_float(v.x << 16) * LOG2E;
            dst[1] = __uint_as_float(v.x & 0xFFFF0000u) * LOG2E;
            dst[2] = __uint_as_float(v.y << 16) * LOG2E;
            dst[3] = __uint_as_float(v.y & 0xFFFF0000u) * LOG2E;
            dst[4] = __uint_as_float(v.z << 16) * LOG2E;
            dst[5] = __uint_as_float(v.z & 0xFFFF0000u) * LOG2E;
            dst[6] = __uint_as_float(v.w << 16) * LOG2E;
            dst[7] = __uint_as_float(v.w & 0xFFFF0000u) * LOG2E;
        }
    } else {
        const float* gbase = (const float*)atoms_v + (size_t)rowBase * P_PRED;
#pragma unroll
        for (int pass = 0; pass < 4; ++pass) {
            int flat = pass * (TPB * 4) + tid * 4;   // 4 f32 / thread
            float4 v = *(const float4*)(gbase + flat);
            int r = flat >> 6, col = flat & 63;
            float* dst = &lds[r * LSTR + col];
            dst[0] = v.x * LOG2E;
            dst[1] = v.y * LOG2E;
            dst[2] = v.z * LOG2E;
            dst[3] = v.w * LOG2E;
        }
    }
    __syncthreads();

    float* a = &lds[row * LSTR];   // atoms row; acc row = a + ACC_OFF

    // ---- clause loop: 32 clauses per wave, wave-uniform records
#pragma unroll 4
    for (int k = 0; k < C_CLS / 4; ++k) {
        const int c = q * (C_CLS / 4) + k;
        const u32* r = recs_u + c * 8;        // s_load_dwordx8
        const u32 w0 = r[0], w1 = r[1], w2 = r[2];
        const float sw0 = __uint_as_float(r[3]);
        const float sw1 = __uint_as_float(r[4]);
        const float sw2 = __uint_as_float(r[5]);
        const u32 i0 = w0 & 0xFFFFu, i1 = w1 & 0xFFFFu, i2 = w2 & 0xFFFFu;
        float L0 = sxor(a[i0], w0 & 0x80000000u);
        float L1 = sxor(a[i1], w1 & 0x80000000u);
        float L2 = sxor(a[i2], w2 & 0x80000000u);
        float e0 = EXP2F(L0), e1 = EXP2F(L1), e2 = EXP2F(L2);
        float t = RCPF(e0 + e1 + e2);
        lds_fadd(&a[i0 + ACC_OFF], (sw0 * t) * e0);
        lds_fadd(&a[i1 + ACC_OFF], (sw1 * t) * e1);
        lds_fadd(&a[i2 + ACC_OFF], (sw2 * t) * e2);
    }
    __syncthreads();

    // ---- epilogue: remap to (row = tid>>2, quarter = tid&3) for coalescing
    {
        const int erow = tid >> 2;
        const int eq = tid & 3;
        const float* arow = &lds[ACC_OFF + erow * LSTR + eq * 16];
        float v[16];
#pragma unroll
        for (int i = 0; i < 16; ++i) v[i] = arow[i];
        if (bf16m) {
            u16* orow = (u16*)out_v + (size_t)(rowBase + erow) * P_PRED + eq * 16;
            uint4 o0, o1;
            o0.x = (u32)f_to_bf16(v[0])  | ((u32)f_to_bf16(v[1])  << 16);
            o0.y = (u32)f_to_bf16(v[2])  | ((u32)f_to_bf16(v[3])  << 16);
            o0.z = (u32)f_to_bf16(v[4])  | ((u32)f_to_bf16(v[5])  << 16);
            o0.w = (u32)f_to_bf16(v[6])  | ((u32)f_to_bf16(v[7])  << 16);
            o1.x = (u32)f_to_bf16(v[8])  | ((u32)f_to_bf16(v[9])  << 16);
            o1.y = (u32)f_to_bf16(v[10]) | ((u32)f_to_bf16(v[11]) << 16);
            o1.z = (u32)f_to_bf16(v[12]) | ((u32)f_to_bf16(v[13]) << 16);
            o1.w = (u32)f_to_bf16(v[14]) | ((u32)f_to_bf16(v[15]) << 16);
            *(uint4*)(orow)     = o0;
            *(uint4*)(orow + 8) = o1;
        } else {
            float* orow = (float*)out_v + (size_t)(rowBase + erow) * P_PRED + eq * 16;
#pragma unroll
            for (int i = 0; i < 16; i += 4)
                *(float4*)(orow + i) = make_float4(v[i], v[i+1], v[i+2], v[i+3]);
        }
    }
}

extern "C" void kernel_launch(void* const* d_in, const int* in_sizes, int n_in,
                              void* d_out, int out_size, void* d_ws, size_t ws_size,
                              hipStream_t stream) {
    const u32* clause_weights = (const u32*)d_in[1]; // bf16 or f32 [128]
    const u32* literal_idx    = (const u32*)d_in[2]; // int32 or int64 [128,3]
    const u32* sign_bits      = (const u32*)d_in[3]; // int32 or int64 [128,3]

    u32* recs  = (u32*)d_ws;                         // 128*32 B = 4 KiB
    u32* flags = (u32*)((char*)d_ws + C_CLS * 32);

    ke_prep<<<1, NPAIR, 0, stream>>>(literal_idx, sign_bits, clause_weights,
                                     recs, flags);
    ke_main<<<B_ROWS / RPB, TPB, 0, stream>>>(d_in[0], recs, flags, d_out);
}

// Round 5
// 335.254 us; speedup vs baseline: 1.0079x; 1.0079x over previous
//
#include <hip/hip_runtime.h>
#include <stdint.h>

typedef unsigned int  u32;
typedef unsigned short u16;

#define B_ROWS 131072
#define P_PRED 64
#define C_CLS  128
#define NPAIR  384               // C*L raw words for dtype detection
#define RPB    64                // rows per block (= lanes; row = tid & 63)
#define TPB    512               // 8 waves: wave q handles 16 clauses
#define CPW    (C_CLS / 8)       // clauses per wave = 16
#define LSTR   65                // LDS row stride (+1 pad -> 2-way bank alias, free)
#define ACC_OFF (RPB * LSTR)     // float-index offset of accumulator region
#define LOG2E  1.4426950408889634f

#if __has_builtin(__builtin_amdgcn_exp2f)
#define EXP2F(x) __builtin_amdgcn_exp2f(x)
#else
#define EXP2F(x) exp2f(x)
#endif

#if __has_builtin(__builtin_amdgcn_rcpf)
#define RCPF(x) __builtin_amdgcn_rcpf(x)
#else
#define RCPF(x) (1.0f / (x))
#endif

__device__ __forceinline__ float bf16_to_f(u16 u) {
    return __uint_as_float(((u32)u) << 16);
}
__device__ __forceinline__ u16 f_to_bf16(float f) {
    u32 u = __float_as_uint(f);
    u += 0x7FFFu + ((u >> 16) & 1u);   // RNE
    return (u16)(u >> 16);
}
__device__ __forceinline__ float sxor(float a, u32 m) {
    return __uint_as_float(__float_as_uint(a) ^ m);
}

// ---------------------------------------------------------------------------
// Prep: dtype detection + 128-entry clause table.
// Clause record (8 dwords = 32 B -> one wave-uniform s_load_dwordx8):
//   r[l]   = idx_l | (sign_l>0 ? 0 : 0x80000000)    l = 0,1,2
//   r[3+l] = sign_l * clamp(weight_c, 0, 500)
// ---------------------------------------------------------------------------
__global__ void ke_prep(const u32* __restrict__ lidx_w,
                        const u32* __restrict__ sb_w,
                        const u32* __restrict__ w_w,
                        u32* __restrict__ recs,     // [128*8] dwords
                        u32* __restrict__ flags) {  // [1]: 1 = bf16 floats
    __shared__ int sidx[NPAIR];
    __shared__ int ssb[NPAIR];
    __shared__ int det[3];  // [0] idx-int64, [1] sb-int64, [2] floats-bf16
    const int t = threadIdx.x;
    if (t < 3) det[t] = 1;
    __syncthreads();
    if (t < NPAIR / 2) {
        if (lidx_w[2 * t + 1] != 0u) det[0] = 0;   // benign race (all write 0)
        if (sb_w[2 * t + 1]   != 0u) det[1] = 0;
    }
    if (t == 0 && (w_w[0] & 0xFFFFu) == 0u) det[2] = 0;
    __syncthreads();
    if (t < NPAIR) {
        sidx[t] = (int)(det[0] ? lidx_w[2 * t] : lidx_w[t]);
        ssb[t]  = (int)(det[1] ? sb_w[2 * t]   : sb_w[t]);
    }
    __syncthreads();
    if (t < C_CLS) {
        const int c = t;
        float wraw = det[2] ? bf16_to_f((u16)(w_w[c / 2] >> ((c & 1) * 16)))
                            : __uint_as_float(w_w[c]);
        float wc = fminf(fmaxf(wraw, 0.0f), 500.0f);
        u32* r = recs + c * 8;
#pragma unroll
        for (int l = 0; l < 3; ++l) {
            int b = ssb[c * 3 + l];
            r[l]     = (u32)sidx[c * 3 + l] | (b ? 0u : 0x80000000u);
            r[3 + l] = __float_as_uint(b ? wc : -wc);
        }
        r[6] = 0u;
        r[7] = 0u;
    }
    if (t == 0) flags[0] = (u32)det[2];
}

// ---------------------------------------------------------------------------
// Main, clause-centric: 64 rows/block staged in LDS (x log2e); accumulator
// region at constant offset. Wave q handles clauses [16q, 16q+16) for all 64
// rows (lane = row). Per clause: 3 ds_read + 3 exp2 + 1 rcp + 3 ds_add_f32.
// atomicAdd is applied DIRECTLY to the __shared__ array expression so the
// compiler's addrspace inference emits ds_add_f32 (R4's decayed-pointer
// __hip_atomic_fetch_add lowered to a flat/CAS path -> 8x regression).
// LDS 33,280 B -> 4 blocks/CU x 8 waves = 32 waves/CU (100% occupancy).
// ---------------------------------------------------------------------------
__global__ __launch_bounds__(TPB, 8)
void ke_main(const void* __restrict__ atoms_v,
             const u32* __restrict__ recs_u,
             const u32* __restrict__ flags,
             void* __restrict__ out_v) {
    __shared__ float lds[2 * RPB * LSTR];   // [0,ACC_OFF): atoms  [ACC_OFF,..): acc
    const int tid = threadIdx.x;
    const int row = tid & (RPB - 1);
    const int q = __builtin_amdgcn_readfirstlane(tid >> 6);  // 0..7, SGPR
    const int rowBase = blockIdx.x * RPB;
    const bool bf16m = (flags[0] != 0u);

    // ---- zero accumulator region
    for (int i = tid; i < RPB * LSTR; i += TPB) lds[ACC_OFF + i] = 0.0f;

    // ---- stage 64 rows of atoms, scaled by log2(e)
    if (bf16m) {
        const u16* gbase = (const u16*)atoms_v + (size_t)rowBase * P_PRED;
        int flat = tid * 8;                       // 512*8 = 4096 = all elems
        uint4 v = *(const uint4*)(gbase + flat);
        int r = flat >> 6, col = flat & 63;
        float* dst = &lds[r * LSTR + col];
        dst[0] = __uint_as_float(v.x << 16) * LOG2E;
        dst[1] = __uint_as_float(v.x & 0xFFFF0000u) * LOG2E;
        dst[2] = __uint_as_float(v.y << 16) * LOG2E;
        dst[3] = __uint_as_float(v.y & 0xFFFF0000u) * LOG2E;
        dst[4] = __uint_as_float(v.z << 16) * LOG2E;
        dst[5] = __uint_as_float(v.z & 0xFFFF0000u) * LOG2E;
        dst[6] = __uint_as_float(v.w << 16) * LOG2E;
        dst[7] = __uint_as_float(v.w & 0xFFFF0000u) * LOG2E;
    } else {
        const float* gbase = (const float*)atoms_v + (size_t)rowBase * P_PRED;
#pragma unroll
        for (int pass = 0; pass < 2; ++pass) {
            int flat = pass * (TPB * 4) + tid * 4;
            float4 v = *(const float4*)(gbase + flat);
            int r = flat >> 6, col = flat & 63;
            float* dst = &lds[r * LSTR + col];
            dst[0] = v.x * LOG2E;
            dst[1] = v.y * LOG2E;
            dst[2] = v.z * LOG2E;
            dst[3] = v.w * LOG2E;
        }
    }
    __syncthreads();

    const int abase = row * LSTR;          // atoms row base (float index)

    // ---- clause loop: 16 clauses per wave, wave-uniform records
#pragma unroll
    for (int k = 0; k < CPW; ++k) {
        const int c = q * CPW + k;
        const u32* r = recs_u + c * 8;        // s_load_dwordx8
        const u32 w0 = r[0], w1 = r[1], w2 = r[2];
        const float sw0 = __uint_as_float(r[3]);
        const float sw1 = __uint_as_float(r[4]);
        const float sw2 = __uint_as_float(r[5]);
        const int i0 = (int)(w0 & 0xFFFFu);
        const int i1 = (int)(w1 & 0xFFFFu);
        const int i2 = (int)(w2 & 0xFFFFu);
        float L0 = sxor(lds[abase + i0], w0 & 0x80000000u);
        float L1 = sxor(lds[abase + i1], w1 & 0x80000000u);
        float L2 = sxor(lds[abase + i2], w2 & 0x80000000u);
        float e0 = EXP2F(L0), e1 = EXP2F(L1), e2 = EXP2F(L2);
        float t = RCPF(e0 + e1 + e2);
        // direct shared-array atomicAdd -> ds_add_f32
        atomicAdd(&lds[ACC_OFF + abase + i0], (sw0 * t) * e0);
        atomicAdd(&lds[ACC_OFF + abase + i1], (sw1 * t) * e1);
        atomicAdd(&lds[ACC_OFF + abase + i2], (sw2 * t) * e2);
    }
    __syncthreads();

    // ---- epilogue: thread -> (row = tid>>3, 8-col chunk = tid&7)
    {
        const int erow = tid >> 3;
        const int ec = (tid & 7) * 8;
        const float* arow = &lds[ACC_OFF + erow * LSTR + ec];
        float v[8];
#pragma unroll
        for (int i = 0; i < 8; ++i) v[i] = arow[i];
        if (bf16m) {
            u16* op = (u16*)out_v + (size_t)(rowBase + erow) * P_PRED + ec;
            uint4 o;
            o.x = (u32)f_to_bf16(v[0]) | ((u32)f_to_bf16(v[1]) << 16);
            o.y = (u32)f_to_bf16(v[2]) | ((u32)f_to_bf16(v[3]) << 16);
            o.z = (u32)f_to_bf16(v[4]) | ((u32)f_to_bf16(v[5]) << 16);
            o.w = (u32)f_to_bf16(v[6]) | ((u32)f_to_bf16(v[7]) << 16);
            *(uint4*)op = o;
        } else {
            float* op = (float*)out_v + (size_t)(rowBase + erow) * P_PRED + ec;
            *(float4*)(op)     = make_float4(v[0], v[1], v[2], v[3]);
            *(float4*)(op + 4) = make_float4(v[4], v[5], v[6], v[7]);
        }
    }
}

extern "C" void kernel_launch(void* const* d_in, const int* in_sizes, int n_in,
                              void* d_out, int out_size, void* d_ws, size_t ws_size,
                              hipStream_t stream) {
    const u32* clause_weights = (const u32*)d_in[1]; // bf16 or f32 [128]
    const u32* literal_idx    = (const u32*)d_in[2]; // int32 or int64 [128,3]
    const u32* sign_bits      = (const u32*)d_in[3]; // int32 or int64 [128,3]

    u32* recs  = (u32*)d_ws;                         // 128*32 B = 4 KiB
    u32* flags = (u32*)((char*)d_ws + C_CLS * 32);

    ke_prep<<<1, NPAIR, 0, stream>>>(literal_idx, sign_bits, clause_weights,
                                     recs, flags);
    ke_main<<<B_ROWS / RPB, TPB, 0, stream>>>(d_in[0], recs, flags, d_out);
}

// Round 6
// 106.934 us; speedup vs baseline: 3.1599x; 3.1351x over previous
//
#include <hip/hip_runtime.h>
#include <stdint.h>

typedef unsigned int  u32;
typedef unsigned short u16;

#define B_ROWS 131072
#define P_PRED 64
#define C_CLS  128
#define NPAIR  384               // C*L raw words for dtype detection
#define CAP    32                // max records per predicate (mean 6)
#define RPB    64                // rows per block (lane = row)
#define TPB    512               // 8 waves; wave q owns predicates [8q, 8q+8)
#define LSTR   129               // LDS row stride in floats (128 exps + 1 pad)
                                 // bank = (row*129 + o)%32 = (row+o)%32 -> 2-way, free
#define LOG2E  1.4426950408889634f

#if __has_builtin(__builtin_amdgcn_exp2f)
#define EXP2F(x) __builtin_amdgcn_exp2f(x)
#else
#define EXP2F(x) exp2f(x)
#endif

#if __has_builtin(__builtin_amdgcn_rcpf)
#define RCPF(x) __builtin_amdgcn_rcpf(x)
#else
#define RCPF(x) (1.0f / (x))
#endif

__device__ __forceinline__ float bf16_to_f(u16 u) {
    return __uint_as_float(((u32)u) << 16);
}
__device__ __forceinline__ u16 f_to_bf16(float f) {
    u32 u = __float_as_uint(f);
    u += 0x7FFFu + ((u >> 16) & 1u);   // RNE
    return (u16)(u >> 16);
}

// ---------------------------------------------------------------------------
// Prep: dtype detection + per-predicate CSR of 4-dword records:
//   r0 = 2*idx_self + (sb_self?0:1)   -- slot of E[±] for the SELF literal
//   r1, r2 = slots of the two OTHER literals
//   r3 = bits of  sign_self * clamp(w_c,0,500)
// where LDS table E[2i] = 2^(+x_i), E[2i+1] = 2^(-x_i).
// NO per-lane LDS atomics anywhere in the hot kernel (R4/R5: ~205 cyc each).
// ---------------------------------------------------------------------------
__global__ void ke_prep(const u32* __restrict__ lidx_w,
                        const u32* __restrict__ sb_w,
                        const u32* __restrict__ w_w,
                        u32* __restrict__ recs,     // [64*CAP*4] dwords
                        int* __restrict__ cnts,     // [64]
                        u32* __restrict__ flags) {  // [1]: 1 = bf16 floats
    __shared__ int scnt[P_PRED];
    __shared__ int sidx[NPAIR];
    __shared__ int ssb[NPAIR];
    __shared__ int det[3];  // [0] idx-int64, [1] sb-int64, [2] floats-bf16
    const int t = threadIdx.x;
    if (t < P_PRED) scnt[t] = 0;
    if (t < 3) det[t] = 1;
    __syncthreads();
    if (t < NPAIR / 2) {
        if (lidx_w[2 * t + 1] != 0u) det[0] = 0;   // benign race (all write 0)
        if (sb_w[2 * t + 1]   != 0u) det[1] = 0;
    }
    if (t == 0 && (w_w[0] & 0xFFFFu) == 0u) det[2] = 0;
    __syncthreads();
    if (t < NPAIR) {
        sidx[t] = (int)(det[0] ? lidx_w[2 * t] : lidx_w[t]);
        ssb[t]  = (int)(det[1] ? sb_w[2 * t]   : sb_w[t]);
    }
    __syncthreads();
    if (t < NPAIR) {
        const int c = t / 3;
        const int l = t - c * 3;
        const int base = c * 3;
        const int o1 = base + (l == 0 ? 1 : 0);
        const int o2 = base + (l == 2 ? 1 : 2);
        const int p = sidx[t];
        const int slot = atomicAdd(&scnt[p], 1);   // 384 ops, prep-only: fine
        float wraw = det[2] ? bf16_to_f((u16)(w_w[c / 2] >> ((c & 1) * 16)))
                            : __uint_as_float(w_w[c]);
        float wc = fminf(fmaxf(wraw, 0.0f), 500.0f);
        if (slot < CAP) {
            u32* r = recs + (p * CAP + slot) * 4;
            r[0] = (u32)(2 * sidx[t]  + (ssb[t]  ? 0 : 1));
            r[1] = (u32)(2 * sidx[o1] + (ssb[o1] ? 0 : 1));
            r[2] = (u32)(2 * sidx[o2] + (ssb[o2] ? 0 : 1));
            r[3] = __float_as_uint(ssb[t] ? wc : -wc);
        }
    }
    __syncthreads();
    if (t < P_PRED) cnts[t] = min(scnt[t], CAP);
    if (t == 0) flags[0] = (u32)det[2];
}

// ---------------------------------------------------------------------------
// Main: stage per-row exp tables E[128] in LDS (both signs of every atom),
// then predicate-centric gather with register accumulators. lane = row,
// wave q owns predicates [8q,8q+8). Records via wave-uniform s_load_dwordx4.
// Per record: 3 ds_read_b32 + 1 v_rcp + ~4 VALU. Zero atomics, one barrier.
// LDS 33,024 B -> 4 blocks/CU x 8 waves = 32 waves/CU.
// ---------------------------------------------------------------------------
__global__ __launch_bounds__(TPB, 8)
void ke_main(const void* __restrict__ atoms_v,
             const u32* __restrict__ recs_u,
             const int* __restrict__ cnts,
             const u32* __restrict__ flags,
             void* __restrict__ out_v) {
    __shared__ float E[RPB * LSTR];
    const int tid = threadIdx.x;
    const int row = tid & (RPB - 1);
    const int grp = __builtin_amdgcn_readfirstlane(tid >> 6);  // 0..7, SGPR
    const int rowBase = blockIdx.x * RPB;
    const bool bf16m = (flags[0] != 0u);

    // ---- stage: 8 atoms/thread -> 16 exps (both signs), contiguous in LDS
    {
        const int srow = tid >> 3;            // 64 rows, 8 threads each
        const int c0 = (tid & 7) * 8;         // first atom col for this thread
        float* dst = &E[srow * LSTR + 2 * c0];
        if (bf16m) {
            const u16* g = (const u16*)atoms_v + (size_t)(rowBase + srow) * P_PRED + c0;
            uint4 v = *(const uint4*)g;
            u32 w[4] = {v.x, v.y, v.z, v.w};
#pragma unroll
            for (int j = 0; j < 4; ++j) {
                float x0 = __uint_as_float(w[j] << 16) * LOG2E;
                float x1 = __uint_as_float(w[j] & 0xFFFF0000u) * LOG2E;
                dst[4 * j + 0] = EXP2F(x0);
                dst[4 * j + 1] = EXP2F(-x0);
                dst[4 * j + 2] = EXP2F(x1);
                dst[4 * j + 3] = EXP2F(-x1);
            }
        } else {
            const float* g = (const float*)atoms_v + (size_t)(rowBase + srow) * P_PRED + c0;
            float4 v0 = *(const float4*)g;
            float4 v1 = *(const float4*)(g + 4);
            float xs[8] = {v0.x, v0.y, v0.z, v0.w, v1.x, v1.y, v1.z, v1.w};
#pragma unroll
            for (int j = 0; j < 8; ++j) {
                float x = xs[j] * LOG2E;
                dst[2 * j + 0] = EXP2F(x);
                dst[2 * j + 1] = EXP2F(-x);
            }
        }
    }
    __syncthreads();

    const float* Lrow = &E[row * LSTR];

    // ---- predicate-centric gather, acc in registers
    float acc[8];
#pragma unroll
    for (int pp = 0; pp < 8; ++pp) {
        const int p = grp * 8 + pp;              // wave-uniform
        const int n = min(cnts[p], CAP);         // s_load
        const u32* rp = recs_u + p * CAP * 4;
        float a = 0.0f;
        for (int e = 0; e < n; ++e) {
            const u32* r = rp + e * 4;           // s_load_dwordx4
            float ss = Lrow[r[0]];
            float s1 = Lrow[r[1]];
            float s2 = Lrow[r[2]];
            float sw = __uint_as_float(r[3]);
            // softmax weight of self literal = ss / (ss+s1+s2)
            a += sw * ss * RCPF(ss + s1 + s2);
        }
        acc[pp] = a;
    }

    // ---- store 8 predicates per thread
    if (bf16m) {
        u16* op = (u16*)out_v + (size_t)(rowBase + row) * P_PRED + grp * 8;
        uint4 o;
        o.x = (u32)f_to_bf16(acc[0]) | ((u32)f_to_bf16(acc[1]) << 16);
        o.y = (u32)f_to_bf16(acc[2]) | ((u32)f_to_bf16(acc[3]) << 16);
        o.z = (u32)f_to_bf16(acc[4]) | ((u32)f_to_bf16(acc[5]) << 16);
        o.w = (u32)f_to_bf16(acc[6]) | ((u32)f_to_bf16(acc[7]) << 16);
        *(uint4*)op = o;
    } else {
        float* op = (float*)out_v + (size_t)(rowBase + row) * P_PRED + grp * 8;
        *(float4*)(op)     = make_float4(acc[0], acc[1], acc[2], acc[3]);
        *(float4*)(op + 4) = make_float4(acc[4], acc[5], acc[6], acc[7]);
    }
}

extern "C" void kernel_launch(void* const* d_in, const int* in_sizes, int n_in,
                              void* d_out, int out_size, void* d_ws, size_t ws_size,
                              hipStream_t stream) {
    const u32* clause_weights = (const u32*)d_in[1]; // bf16 or f32 [128]
    const u32* literal_idx    = (const u32*)d_in[2]; // int32 or int64 [128,3]
    const u32* sign_bits      = (const u32*)d_in[3]; // int32 or int64 [128,3]

    u32* recs  = (u32*)d_ws;                              // 64*32*16 B = 32 KiB
    int* cnts  = (int*)((char*)d_ws + P_PRED * CAP * 16); // 256 B
    u32* flags = (u32*)((char*)d_ws + P_PRED * CAP * 16 + 256);

    ke_prep<<<1, NPAIR, 0, stream>>>(literal_idx, sign_bits, clause_weights,
                                     recs, cnts, flags);
    ke_main<<<B_ROWS / RPB, TPB, 0, stream>>>(d_in[0], recs, cnts, flags, d_out);
}